// Round 3
// baseline (230.602 us; speedup 1.0000x reference)
//
#include <hip/hip_runtime.h>

#define S_VOX (128*128*128)   // spatial voxels per (b,n) plane = 2097152
#define QV (S_VOX/4)          // float4 groups per plane = 524288
#define BLOCKS_PER_PLANE 128
#define CHUNK_Q (QV / BLOCKS_PER_PLANE)   // 4096 q-groups per block
#define EPSF 1e-10f
#define SMOOTHF 1e-5f

// ws layout (floats): [0] ce_sum, [1+plane] inter, [17+plane] ground, [33+plane] pred_o
// where plane = b*8+n
#define NACC 49

__device__ __forceinline__ float wave_reduce(float v) {
#pragma unroll
    for (int off = 32; off > 0; off >>= 1)
        v += __shfl_down(v, off, 64);
    return v;
}

// Plane-major decomposition: block = (plane, chunk). Each block reads a
// CONTIGUOUS 64 KB chunk of one pred plane + the matching 64 KB chunks of both
// target arrays (3 streams/thread, 4 accumulators/thread). CE decomposes as
//   ce_total = sum_{b,b',vox} log(pred[b, t[b',vox], vox] + EPS)
// and the (b,n)-plane contributes (t[b]==n) + (t[1-b]==n) copies of
// log(pred[b,n,vox]+EPS) — fully plane-local.
// Block id is plane-major (id = plane*128 + chunk) so id%8 == chunk%8: with
// round-robin XCD dispatch, all 16 planes of a chunk share one XCD, whose L2
// serves 15 of the 16 target-chunk re-reads. Pred streams are long sequential
// runs -> DRAM row hits -> lower latency -> higher throughput under the
// per-CU outstanding-miss cap (the round-0/1 bottleneck theory).
__global__ __launch_bounds__(256) void dice_main(const float* __restrict__ pred,
                                                 const int* __restrict__ tgt,
                                                 float* __restrict__ ws) {
    const int plane = blockIdx.x >> 7;    // 0..15  (= b*8+n)
    const int chunk = blockIdx.x & 127;   // 0..127
    const int b = plane >> 3;
    const int n = plane & 7;

    const float4* p4 = (const float4*)pred + (size_t)plane * QV + (size_t)chunk * CHUNK_Q;
    const int4*   ta = (const int4*)tgt + (size_t)b * QV        + (size_t)chunk * CHUNK_Q;
    const int4*   tb = (const int4*)tgt + (size_t)(1 - b) * QV  + (size_t)chunk * CHUNK_Q;

    float po = 0.f, inter = 0.f, ce = 0.f;
    int gc = 0;

#pragma unroll 4
    for (int i = threadIdx.x; i < CHUNK_Q; i += 256) {
        const float4 p  = p4[i];
        const int4   t0 = ta[i];
        const int4   t1 = tb[i];
        po += (p.x + p.y) + (p.z + p.w);
#define SLOT(pv, u, v)                                          \
        {                                                       \
            const int m0 = ((u) == n);                          \
            const int m1 = ((v) == n);                          \
            inter += m0 ? (pv) : 0.f;                           \
            gc    += m0;                                        \
            ce    += (float)(m0 + m1) * __logf((pv) + EPSF);    \
        }
        SLOT(p.x, t0.x, t1.x)
        SLOT(p.y, t0.y, t1.y)
        SLOT(p.z, t0.z, t1.z)
        SLOT(p.w, t0.w, t1.w)
#undef SLOT
    }

    // ---- block reduction: 4 scalars ----
    __shared__ float red[4][4];
    const int lane = threadIdx.x & 63;
    const int wave = threadIdx.x >> 6;
    float acc[4] = { ce, inter, (float)gc, po };
#pragma unroll
    for (int i = 0; i < 4; i++) {
        float v = wave_reduce(acc[i]);
        if (lane == 0) red[wave][i] = v;
    }
    __syncthreads();
    if (threadIdx.x < 4) {
        const int i = threadIdx.x;
        const float s = red[0][i] + red[1][i] + red[2][i] + red[3][i];
        int dst;
        if (i == 0)      dst = 0;             // ce
        else if (i == 1) dst = 1  + plane;    // inter
        else if (i == 2) dst = 17 + plane;    // ground
        else             dst = 33 + plane;    // pred_o
        atomicAdd(&ws[dst], s);
    }
}

__global__ void dice_finalize(const float* __restrict__ ws, float* __restrict__ out) {
    const int i = threadIdx.x;
    float term = 0.f;
    if (i < 16) {
        float inter = ws[1 + i];
        float g     = ws[17 + i];
        float p     = ws[33 + i];
        term = 1.0f - (2.0f * inter + SMOOTHF) / (g + p + SMOOTHF);
    }
    term = wave_reduce(term);
    if (i == 0) {
        // celoss = -ce_sum / (B*B*S)  with B=2
        float celoss = -ws[0] / (4.0f * (float)S_VOX);
        out[0] = celoss + term * (1.0f / 16.0f);
    }
}

extern "C" void kernel_launch(void* const* d_in, const int* in_sizes, int n_in,
                              void* d_out, int out_size, void* d_ws, size_t ws_size,
                              hipStream_t stream) {
    const float* pred = (const float*)d_in[0];
    const int*   tgt  = (const int*)d_in[1];
    float* ws  = (float*)d_ws;
    float* out = (float*)d_out;

    hipMemsetAsync(ws, 0, NACC * sizeof(float), stream);
    // 2048 blocks = 16 planes x 128 chunks, 256 threads, 16 iters/thread
    dice_main<<<16 * BLOCKS_PER_PLANE, 256, 0, stream>>>(pred, tgt, ws);
    dice_finalize<<<1, 64, 0, stream>>>(ws, out);
}

// Round 4
// 230.276 us; speedup vs baseline: 1.0014x; 1.0014x over previous
//
#include <hip/hip_runtime.h>

#define S_VOX (128*128*128)   // spatial voxels per (b,n) plane = 2097152
#define QV (S_VOX/4)          // float4 groups per plane = 524288
#define CHUNKS 512
#define CHUNK_Q (QV / CHUNKS) // 1024 q-groups per block per stream
#define EPSF 1e-10f
#define SMOOTHF 1e-5f

// ws layout (floats): [0] ce_sum, [1+plane] inter, [17+plane] ground, [33+plane] pred_o
// where plane = b*8+n
#define NACC 49

__device__ __forceinline__ float wave_reduce(float v) {
#pragma unroll
    for (int off = 32; off > 0; off >>= 1)
        v += __shfl_down(v, off, 64);
    return v;
}

// Latency-bound fix (rounds 0-3 all ~85us at 2TB/s regardless of structure,
// VGPR=20 -> compiler emitted 3-loads+vmcnt(0) per iter = 16 serial round
// trips): each block covers FOUR planes (b in {0,1}) x (n in {2j,2j+1}) of one
// contiguous chunk, 4 iters/thread, and ALL 24 loads are issued into named
// registers up front (96 data VGPRs, ~24KB in flight per wave) before any
// consume -> one latency exposure instead of 16. Target demand drops 256->64MB
// since one block serves 4 planes from 2 target streams. Sharer blocks of a
// chunk are consecutive ids -> L2/LLC temporal locality.
// CE decomposition: ce = sum_{b,b',vox} log(pred[b, t[b',vox], vox] + EPS);
// plane (b,n) contributes c_n = (t0==n)+(t1==n) copies of log(pred[b,n]+EPS),
// and c_n is batch-independent -> fold pairs: c0*log((p00+E)*(p10+E)).
__global__ __launch_bounds__(256, 3) void dice_main(const float* __restrict__ pred,
                                                    const int* __restrict__ tgt,
                                                    float* __restrict__ ws) {
    const int chunk = blockIdx.x >> 2;   // 0..511
    const int j     = blockIdx.x & 3;    // n-pair: n in {2j, 2j+1}
    const int n0 = 2 * j;

    const size_t cb = (size_t)chunk * CHUNK_Q;
    const float4* p00 = (const float4*)pred + (size_t)(n0     ) * QV + cb; // b0,n0
    const float4* p01 = (const float4*)pred + (size_t)(n0 +  1) * QV + cb; // b0,n0+1
    const float4* p10 = (const float4*)pred + (size_t)(n0 +  8) * QV + cb; // b1,n0
    const float4* p11 = (const float4*)pred + (size_t)(n0 +  9) * QV + cb; // b1,n0+1
    const int4*   t0p = (const int4*)tgt + cb;                 // batch-0 target
    const int4*   t1p = (const int4*)tgt + (size_t)QV + cb;    // batch-1 target

    float ce = 0.f;
    float inter[4] = {0.f,0.f,0.f,0.f};
    float po[4]    = {0.f,0.f,0.f,0.f};
    int   gc[4]    = {0,0,0,0};
    // local plane l: b = l>>1, n = n0 + (l&1); global plane = (l>>1)*8 + n0 + (l&1)

    const int i0 = threadIdx.x;

    // ---- issue ALL loads up front: 24 vector loads, 96 data VGPRs ----
    float4 A0[4], A1[4], A2[4], A3[4];
    int4   TA[4], TB[4];
#pragma unroll
    for (int k = 0; k < 4; k++) {
        const int i = i0 + k * 256;
        A0[k] = p00[i];
        A1[k] = p01[i];
        A2[k] = p10[i];
        A3[k] = p11[i];
        TA[k] = t0p[i];
        TB[k] = t1p[i];
    }

    // ---- consume in issue order (compiler emits counted vmcnt) ----
#pragma unroll
    for (int k = 0; k < 4; k++) {
        const int4 ta = TA[k], tb = TB[k];
        const float4 q0 = A0[k], q1 = A1[k], q2 = A2[k], q3 = A3[k];

#define VOXEL(pa, pb, pc, pd, u, v)                                     \
        {                                                               \
            const int ua = ((u) == n0);                                 \
            const int ub = ((u) == n0 + 1);                             \
            const int va = ((v) == n0);                                 \
            const int vb = ((v) == n0 + 1);                             \
            inter[0] += ua ? (pa) : 0.f;  gc[0] += ua;                  \
            inter[1] += ub ? (pb) : 0.f;  gc[1] += ub;                  \
            inter[2] += va ? (pc) : 0.f;  gc[2] += va;                  \
            inter[3] += vb ? (pd) : 0.f;  gc[3] += vb;                  \
            ce += (float)(ua + va) * __logf(((pa) + EPSF) * ((pc) + EPSF)); \
            ce += (float)(ub + vb) * __logf(((pb) + EPSF) * ((pd) + EPSF)); \
            po[0] += (pa); po[1] += (pb); po[2] += (pc); po[3] += (pd); \
        }
        VOXEL(q0.x, q1.x, q2.x, q3.x, ta.x, tb.x)
        VOXEL(q0.y, q1.y, q2.y, q3.y, ta.y, tb.y)
        VOXEL(q0.z, q1.z, q2.z, q3.z, ta.z, tb.z)
        VOXEL(q0.w, q1.w, q2.w, q3.w, ta.w, tb.w)
#undef VOXEL
    }

    // ---- block reduction: 13 scalars ----
    __shared__ float red[4][13];
    const int lane = threadIdx.x & 63;
    const int wave = threadIdx.x >> 6;
    float acc[13];
    acc[0] = ce;
#pragma unroll
    for (int l = 0; l < 4; l++) {
        acc[1 + l] = inter[l];
        acc[5 + l] = (float)gc[l];
        acc[9 + l] = po[l];
    }
#pragma unroll
    for (int i = 0; i < 13; i++) {
        float v = wave_reduce(acc[i]);
        if (lane == 0) red[wave][i] = v;
    }
    __syncthreads();
    if (threadIdx.x < 13) {
        const int i = threadIdx.x;
        const float s = red[0][i] + red[1][i] + red[2][i] + red[3][i];
        int dst;
        if (i == 0) {
            dst = 0;                                        // ce
        } else {
            const int l = (i - 1) & 3;                      // local plane
            const int plane = ((l >> 1) * 8) + n0 + (l & 1);
            if (i <= 4)      dst = 1  + plane;              // inter
            else if (i <= 8) dst = 17 + plane;              // ground
            else             dst = 33 + plane;              // pred_o
        }
        atomicAdd(&ws[dst], s);
    }
}

__global__ void dice_finalize(const float* __restrict__ ws, float* __restrict__ out) {
    const int i = threadIdx.x;
    float term = 0.f;
    if (i < 16) {
        float inter = ws[1 + i];
        float g     = ws[17 + i];
        float p     = ws[33 + i];
        term = 1.0f - (2.0f * inter + SMOOTHF) / (g + p + SMOOTHF);
    }
    term = wave_reduce(term);
    if (i == 0) {
        // celoss = -ce_sum / (B*B*S)  with B=2
        float celoss = -ws[0] / (4.0f * (float)S_VOX);
        out[0] = celoss + term * (1.0f / 16.0f);
    }
}

extern "C" void kernel_launch(void* const* d_in, const int* in_sizes, int n_in,
                              void* d_out, int out_size, void* d_ws, size_t ws_size,
                              hipStream_t stream) {
    const float* pred = (const float*)d_in[0];
    const int*   tgt  = (const int*)d_in[1];
    float* ws  = (float*)d_ws;
    float* out = (float*)d_out;

    hipMemsetAsync(ws, 0, NACC * sizeof(float), stream);
    // 2048 blocks = 512 chunks x 4 plane-groups; 4 iters/thread, all loads up front
    dice_main<<<CHUNKS * 4, 256, 0, stream>>>(pred, tgt, ws);
    dice_finalize<<<1, 64, 0, stream>>>(ws, out);
}